// Round 15
// baseline (1245.262 us; speedup 1.0000x reference)
//
#include <hip/hip_runtime.h>
#include <hip/hip_bf16.h>

#define H 128
#define ND 4096
#define CH 8      // waves (group-chunks) per drug
#define MAXG 128  // gl2 slots per drug (observed max ~77; 128 = 11 sigma)
#define ZDW (ND + ND * H + ND)   // dwords to zero: gcnt | dsum | done

__device__ __forceinline__ float lof(unsigned u) { return __uint_as_float(u << 16); }
__device__ __forceinline__ float hif(unsigned u) { return __uint_as_float(u & 0xffff0000u); }

// Select component `slot` (0..3) of a uniform uint4 -- 3 v_cndmask.
__device__ __forceinline__ unsigned sel4(uint4 q, int slot) {
    unsigned a = (slot & 1) ? q.y : q.x;
    unsigned b = (slot & 1) ? q.w : q.z;
    return (slot & 2) ? b : a;
}

// K1: psexp[p] = exp(ph[p].w_attn)  AND  phb[p] = bf16(ph[p]).
// Two rows per wave (32 lanes x float4 per row), one pass over the table.
// Also zeroes gcnt|dsum|done (contiguous) and gs -- no separate memset.
__global__ void k_pscore_cvt(const float* __restrict__ ph,
                             const float* __restrict__ w_attn,
                             float* __restrict__ psexp,
                             __hip_bfloat16* __restrict__ phb,
                             int* __restrict__ zbase,
                             int* __restrict__ gs, int NP, int G) {
    int gt = blockIdx.x * blockDim.x + threadIdx.x;
    int nthr = gridDim.x * blockDim.x;
    for (int i = gt; i < ZDW; i += nthr) zbase[i] = 0;
    for (int i = gt; i < G; i += nthr) gs[i] = 0;
    int lane = threadIdx.x & 63;
    int half = lane >> 5;
    int l32  = lane & 31;
    int wid  = gt >> 6;
    int row  = wid * 2 + half;
    if (row >= NP) return;
    float4 wa = *(const float4*)(w_attn + 4 * l32);
    float4 v  = *(const float4*)(ph + (size_t)row * H + 4 * l32);
    __hip_bfloat16 b0 = __float2bfloat16(v.x);
    __hip_bfloat16 b1 = __float2bfloat16(v.y);
    __hip_bfloat16 b2 = __float2bfloat16(v.z);
    __hip_bfloat16 b3 = __float2bfloat16(v.w);
    ushort4 pk;
    pk.x = *(unsigned short*)&b0; pk.y = *(unsigned short*)&b1;
    pk.z = *(unsigned short*)&b2; pk.w = *(unsigned short*)&b3;
    *(ushort4*)(phb + (size_t)row * H + 4 * l32) = pk;
    float d = v.x * wa.x + v.y * wa.y + v.z * wa.z + v.w * wa.w;
    #pragma unroll
    for (int off = 16; off >= 1; off >>= 1) d += __shfl_xor(d, off, 64);
    if (l32 == 0) psexp[row] = __expf(d);   // raw exp: scores ~N(0,1), f32-safe
}

// K_prep: pure streaming -- NO serial walk. pw[t] = idx|bf16(weight)<<16
// (coalesced); boundary MARKS from neighbor compares (gid[t-1], gid[t+1]
// are L1 hits). gs[g] = start+1 (0 = empty, gs pre-zeroed in K1); ge[g] = end.
__global__ void k_prep(const int* __restrict__ gid,
                       const int* __restrict__ prot_idx,
                       const float* __restrict__ psexp,
                       int* __restrict__ gs, int* __restrict__ ge,
                       unsigned* __restrict__ pw, int E) {
    int t = blockIdx.x * blockDim.x + threadIdx.x;
    if (t >= E) return;
    int p = prot_idx[t];
    __hip_bfloat16 hb = __float2bfloat16(psexp[p]);
    pw[t] = (unsigned)p | ((unsigned)*(unsigned short*)&hb << 16);
    int g  = gid[t];
    int gp = (t > 0) ? gid[t - 1] : -1;
    int gn = (t + 1 < E) ? gid[t + 1] : -1;
    if (gp != g) gs[g] = t + 1;
    if (gn != g) ge[g] = t + 1;
}

// K_p2: per-group list build: {start,len} appended to the owning drug.
__global__ void k_p2(const int* __restrict__ gs, const int* __restrict__ ge,
                     const int* __restrict__ g2d,
                     int* __restrict__ gcnt, int2* __restrict__ gl2, int G) {
    int g = blockIdx.x * blockDim.x + threadIdx.x;
    if (g >= G) return;
    int s = gs[g];
    if (s) {
        int start = s - 1;
        int len = ge[g] - start;
        int d = g2d[g];
        int slot = atomicAdd(&gcnt[d], 1);
        if (slot < MAXG) gl2[d * MAXG + slot] = make_int2(start, len);
    }
}

// K_fused_drug: one wave per (drug, chunk) -- r13 hot loop verbatim -- PLUS
// fused output projection: after the dsum flush, threadfence + done-counter;
// the LAST of the drug's 8 waves reads back dsum, divides by gcnt, and
// computes the drug's out row (w_out 64KB L2-resident). Removes the k4
// dispatch entirely.
__global__ void k_fused_drug(const __hip_bfloat16* __restrict__ phb,
                             const unsigned* __restrict__ pw,
                             const int2* __restrict__ gl2,
                             const int* __restrict__ gcnt,
                             const float* __restrict__ w_out,
                             const float* __restrict__ b_out,
                             float* __restrict__ dsum,
                             int* __restrict__ done,
                             float* __restrict__ out) {
    __shared__ float xbuf[4][H];
    int w    = threadIdx.x >> 6;
    int lane = threadIdx.x & 63;
    int slot = lane >> 4;
    int sub  = lane & 15;
    int wid  = (blockIdx.x * blockDim.x + threadIdx.x) >> 6;
    wid = __builtin_amdgcn_readfirstlane(wid);   // wave-uniform -> SGPR
    int d = wid >> 3;          // wid / CH
    int c = wid & (CH - 1);
    if (d >= ND) return;
    int gn = gcnt[d];
    if (gn > MAXG) gn = MAXG;
    const int2* gl = gl2 + d * MAXG;
    const __hip_bfloat16* base = phb + sub * 8;
    float ax[8];
    #pragma unroll
    for (int k = 0; k < 8; ++k) ax[k] = 0.f;
    for (int i = c; i < gn; i += CH) {
        int2 A = gl[i];
        int s0  = __builtin_amdgcn_readfirstlane(A.x);
        int len = __builtin_amdgcn_readfirstlane(A.y);
        float sa = 0.f;
        float gx[8];
        #pragma unroll
        for (int k = 0; k < 8; ++k) gx[k] = 0.f;
        for (int e = 0; e < len; e += 16) {
            const uint4* pp = (const uint4*)(pw + s0 + e);  // uniform -> s_load
            uint4 q[4];
            q[0] = pp[0]; q[1] = pp[1]; q[2] = pp[2]; q[3] = pp[3];
            int rem = len - e;
            int p0 = (int)(q[0].x & 0xffffu);
            float wv[4]; int pv[4];
            #pragma unroll
            for (int j = 0; j < 4; ++j) {
                unsigned uv = sel4(q[j], slot);
                int ii = 4 * j + slot;
                bool valid = ii < rem;
                wv[j] = valid ? hif(uv) : 0.f;
                pv[j] = valid ? (int)(uv & 0xffffu) : p0;
            }
            uint4 rr[4];
            #pragma unroll
            for (int j = 0; j < 4; ++j)
                if (4 * j < rem) rr[j] = *(const uint4*)(base + (size_t)pv[j] * H);
            #pragma unroll
            for (int j = 0; j < 4; ++j)
                if (4 * j < rem) {
                    sa += wv[j];
                    gx[0] += wv[j] * lof(rr[j].x);
                    gx[1] += wv[j] * hif(rr[j].x);
                    gx[2] += wv[j] * lof(rr[j].y);
                    gx[3] += wv[j] * hif(rr[j].y);
                    gx[4] += wv[j] * lof(rr[j].z);
                    gx[5] += wv[j] * hif(rr[j].z);
                    gx[6] += wv[j] * lof(rr[j].w);
                    gx[7] += wv[j] * hif(rr[j].w);
                }
        }
        float st = sa;                        // entries split across slots
        st += __shfl_xor(st, 16, 64);
        st += __shfl_xor(st, 32, 64);
        float inv = 1.0f / st;
        #pragma unroll
        for (int k = 0; k < 8; ++k) ax[k] += gx[k] * inv;
    }
    #pragma unroll
    for (int k = 0; k < 8; ++k) {
        ax[k] += __shfl_xor(ax[k], 16, 64);
        ax[k] += __shfl_xor(ax[k], 32, 64);
    }
    // per-wave LDS transpose (same-wave ds ordering, no barrier needed)
    if (slot == 0) {
        *(float4*)&xbuf[w][8 * sub]     = make_float4(ax[0], ax[1], ax[2], ax[3]);
        *(float4*)&xbuf[w][8 * sub + 4] = make_float4(ax[4], ax[5], ax[6], ax[7]);
    }
    float2 f2 = *(const float2*)&xbuf[w][2 * lane];
    float* dst = dsum + (size_t)d * H + 2 * lane;
    atomicAdd(dst,     f2.x);
    atomicAdd(dst + 1, f2.y);

    // ---- fused epilogue: last wave of this drug does the output projection
    __threadfence();
    int old = 0;
    if (lane == 0) old = atomicAdd(&done[d], 1);
    old = __shfl(old, 0, 64);
    if (old == CH - 1) {
        __threadfence();   // acquire: see all 8 waves' dsum atomics
        int cdrug = gcnt[d];
        float cinv = (cdrug > 0) ? 1.0f / (float)cdrug : 0.f;
        float2 fb = *(const float2*)(dsum + (size_t)d * H + 2 * lane);
        xbuf[w][2 * lane]     = fb.x * cinv;
        xbuf[w][2 * lane + 1] = fb.y * cinv;
        int j0 = 2 * lane;
        const float4* f4p = (const float4*)xbuf[w];
        const float4* wr0 = (const float4*)(w_out + (size_t)j0 * H);
        const float4* wr1 = (const float4*)(w_out + (size_t)(j0 + 1) * H);
        float a0 = 0.f, a1 = 0.f;
        for (int i = 0; i < H / 4; ++i) {
            float4 f4 = f4p[i];
            float4 wa4 = wr0[i];
            float4 wb4 = wr1[i];
            a0 += f4.x * wa4.x + f4.y * wa4.y + f4.z * wa4.z + f4.w * wa4.w;
            a1 += f4.x * wb4.x + f4.y * wb4.y + f4.z * wb4.z + f4.w * wb4.w;
        }
        a0 += b_out[j0];
        a1 += b_out[j0 + 1];
        float2 o;
        o.x = fmaxf(a0, 0.f);
        o.y = fmaxf(a1, 0.f);
        *(float2*)(out + (size_t)d * H + j0) = o;
    }
}

extern "C" void kernel_launch(void* const* d_in, const int* in_sizes, int n_in,
                              void* d_out, int out_size, void* d_ws, size_t ws_size,
                              hipStream_t stream) {
    const float* protein_h = (const float*)d_in[0];
    const float* w_attn    = (const float*)d_in[1];
    const float* w_out     = (const float*)d_in[2];
    const float* b_out     = (const float*)d_in[3];
    const int*   prot_idx  = (const int*)d_in[4];
    const int*   group_ids = (const int*)d_in[5];
    const int*   g2d       = (const int*)d_in[6];

    const int E  = in_sizes[4];
    const int G  = in_sizes[6];
    const int NP = in_sizes[0] / H;

    // Workspace (~28.6 MB):
    // phb | psexp | pw(+16) | gs | ge | gl2 | [ZERO: gcnt dsum done]
    __hip_bfloat16* phb = (__hip_bfloat16*)d_ws;          // NP*H bf16
    float*    psexp = (float*)(phb + (size_t)NP * H);     // NP
    unsigned* pw    = (unsigned*)(psexp + NP);            // E + 16
    int*      gs    = (int*)(pw + E + 16);                // G (zeroed in k1)
    int*      ge    = gs + G;                             // G
    int2*     gl2   = (int2*)(ge + G);                    // ND*MAXG
    int*      gcnt  = (int*)(gl2 + (size_t)ND * MAXG);    // ND   (zeroed in k1)
    float*    dsum  = (float*)(gcnt + ND);                // ND*H (zeroed in k1)
    int*      done  = (int*)(dsum + (size_t)ND * H);      // ND   (zeroed in k1)

    // Per-protein exp(logit) + bf16 table + accumulator/flag zeroing.
    int pw_blocks = (NP + 7) / 8;
    k_pscore_cvt<<<pw_blocks, 256, 0, stream>>>(protein_h, w_attn, psexp, phb,
                                                gcnt, gs, NP, G);

    // Streaming marks + fused per-entry stream (idx|bf16 weight).
    k_prep<<<(E + 255) / 256, 256, 0, stream>>>(group_ids, prot_idx, psexp,
                                                gs, ge, pw, E);

    // Per-group {start,len} -> drug lists.
    k_p2<<<(G + 255) / 256, 256, 0, stream>>>(gs, ge, g2d, gcnt, gl2, G);

    // Drug-major fused pooling + fused output projection (last-wave).
    k_fused_drug<<<(ND * CH) / 4, 256, 0, stream>>>(phb, pw, gl2, gcnt,
                                                    w_out, b_out, dsum, done,
                                                    (float*)d_out);
}

// Round 16
// 147.761 us; speedup vs baseline: 8.4276x; 8.4276x over previous
//
#include <hip/hip_runtime.h>
#include <hip/hip_bf16.h>

#define H 128
#define ND 4096
#define CH 8      // waves (group-chunks) per drug
#define MAXG 128  // gl2 slots per drug (observed max ~77; 128 = 11 sigma)
#define ZDW (ND + ND * H)   // dwords to zero: gcnt | dsum

__device__ __forceinline__ float lof(unsigned u) { return __uint_as_float(u << 16); }
__device__ __forceinline__ float hif(unsigned u) { return __uint_as_float(u & 0xffff0000u); }

// Select component `slot` (0..3) of a uniform uint4 -- 3 v_cndmask.
__device__ __forceinline__ unsigned sel4(uint4 q, int slot) {
    unsigned a = (slot & 1) ? q.y : q.x;
    unsigned b = (slot & 1) ? q.w : q.z;
    return (slot & 2) ? b : a;
}

// K1: psexp[p] = exp(ph[p].w_attn)  AND  phb[p] = bf16(ph[p]).
// Two rows per wave (32 lanes x float4 per row), one pass over the table.
// Also zeroes gcnt|dsum (contiguous) and gs -- no separate memset.
__global__ void k_pscore_cvt(const float* __restrict__ ph,
                             const float* __restrict__ w_attn,
                             float* __restrict__ psexp,
                             __hip_bfloat16* __restrict__ phb,
                             int* __restrict__ zbase,
                             int* __restrict__ gs, int NP, int G) {
    int gt = blockIdx.x * blockDim.x + threadIdx.x;
    int nthr = gridDim.x * blockDim.x;
    for (int i = gt; i < ZDW; i += nthr) zbase[i] = 0;
    for (int i = gt; i < G; i += nthr) gs[i] = 0;
    int lane = threadIdx.x & 63;
    int half = lane >> 5;
    int l32  = lane & 31;
    int wid  = gt >> 6;
    int row  = wid * 2 + half;
    if (row >= NP) return;
    float4 wa = *(const float4*)(w_attn + 4 * l32);
    float4 v  = *(const float4*)(ph + (size_t)row * H + 4 * l32);
    __hip_bfloat16 b0 = __float2bfloat16(v.x);
    __hip_bfloat16 b1 = __float2bfloat16(v.y);
    __hip_bfloat16 b2 = __float2bfloat16(v.z);
    __hip_bfloat16 b3 = __float2bfloat16(v.w);
    ushort4 pk;
    pk.x = *(unsigned short*)&b0; pk.y = *(unsigned short*)&b1;
    pk.z = *(unsigned short*)&b2; pk.w = *(unsigned short*)&b3;
    *(ushort4*)(phb + (size_t)row * H + 4 * l32) = pk;
    float d = v.x * wa.x + v.y * wa.y + v.z * wa.z + v.w * wa.w;
    #pragma unroll
    for (int off = 16; off >= 1; off >>= 1) d += __shfl_xor(d, off, 64);
    if (l32 == 0) psexp[row] = __expf(d);   // raw exp: scores ~N(0,1), f32-safe
}

// K_prep: pure streaming -- NO serial walk, NO fences. pw[t] =
// idx|bf16(weight)<<16 (coalesced); boundary MARKS from neighbor compares
// (gid[t-1], gid[t+1] are L1 hits). gs[g] = start+1 (0 = empty, pre-zeroed);
// ge[g] = end.
__global__ void k_prep(const int* __restrict__ gid,
                       const int* __restrict__ prot_idx,
                       const float* __restrict__ psexp,
                       int* __restrict__ gs, int* __restrict__ ge,
                       unsigned* __restrict__ pw, int E) {
    int t = blockIdx.x * blockDim.x + threadIdx.x;
    if (t >= E) return;
    int p = prot_idx[t];
    __hip_bfloat16 hb = __float2bfloat16(psexp[p]);
    pw[t] = (unsigned)p | ((unsigned)*(unsigned short*)&hb << 16);
    int g  = gid[t];
    int gp = (t > 0) ? gid[t - 1] : -1;
    int gn = (t + 1 < E) ? gid[t + 1] : -1;
    if (gp != g) gs[g] = t + 1;
    if (gn != g) ge[g] = t + 1;
}

// K_p2: per-group list build: {start,len} appended to the owning drug.
__global__ void k_p2(const int* __restrict__ gs, const int* __restrict__ ge,
                     const int* __restrict__ g2d,
                     int* __restrict__ gcnt, int2* __restrict__ gl2, int G) {
    int g = blockIdx.x * blockDim.x + threadIdx.x;
    if (g >= G) return;
    int s = gs[g];
    if (s) {
        int start = s - 1;
        int len = ge[g] - start;
        int d = g2d[g];
        int slot = atomicAdd(&gcnt[d], 1);
        if (slot < MAXG) gl2[d * MAXG + slot] = make_int2(start, len);
    }
}

// K_fused_drug: one wave per (drug, chunk) -- r13 hot loop VERBATIM (no
// fences, no done-counter; those cost 16x in r15). lane = (slot=lane>>4,
// sub=lane&15); scalar s_load pw quads; 3-cndmask lane distribution; uint4
// gather = 4 complete 256B rows/instr; quad guards skip tail; shfl_xor
// denom; per-wave LDS transpose flush, 2 full-wave atomic instructions.
__global__ void k_fused_drug(const __hip_bfloat16* __restrict__ phb,
                             const unsigned* __restrict__ pw,
                             const int2* __restrict__ gl2,
                             const int* __restrict__ gcnt,
                             float* __restrict__ dsum) {
    __shared__ float xbuf[4][H];
    int w    = threadIdx.x >> 6;
    int lane = threadIdx.x & 63;
    int slot = lane >> 4;
    int sub  = lane & 15;
    int wid  = (blockIdx.x * blockDim.x + threadIdx.x) >> 6;
    wid = __builtin_amdgcn_readfirstlane(wid);   // wave-uniform -> SGPR
    int d = wid >> 3;          // wid / CH
    int c = wid & (CH - 1);
    if (d >= ND) return;
    int gn = gcnt[d];
    if (gn > MAXG) gn = MAXG;
    const int2* gl = gl2 + d * MAXG;
    const __hip_bfloat16* base = phb + sub * 8;
    float ax[8];
    #pragma unroll
    for (int k = 0; k < 8; ++k) ax[k] = 0.f;
    for (int i = c; i < gn; i += CH) {
        int2 A = gl[i];
        int s0  = __builtin_amdgcn_readfirstlane(A.x);
        int len = __builtin_amdgcn_readfirstlane(A.y);
        float sa = 0.f;
        float gx[8];
        #pragma unroll
        for (int k = 0; k < 8; ++k) gx[k] = 0.f;
        for (int e = 0; e < len; e += 16) {
            const uint4* pp = (const uint4*)(pw + s0 + e);  // uniform -> s_load
            uint4 q[4];
            q[0] = pp[0]; q[1] = pp[1]; q[2] = pp[2]; q[3] = pp[3];
            int rem = len - e;
            int p0 = (int)(q[0].x & 0xffffu);
            float wv[4]; int pv[4];
            #pragma unroll
            for (int j = 0; j < 4; ++j) {
                unsigned uv = sel4(q[j], slot);
                int ii = 4 * j + slot;
                bool valid = ii < rem;
                wv[j] = valid ? hif(uv) : 0.f;
                pv[j] = valid ? (int)(uv & 0xffffu) : p0;
            }
            uint4 rr[4];
            #pragma unroll
            for (int j = 0; j < 4; ++j)
                if (4 * j < rem) rr[j] = *(const uint4*)(base + (size_t)pv[j] * H);
            #pragma unroll
            for (int j = 0; j < 4; ++j)
                if (4 * j < rem) {
                    sa += wv[j];
                    gx[0] += wv[j] * lof(rr[j].x);
                    gx[1] += wv[j] * hif(rr[j].x);
                    gx[2] += wv[j] * lof(rr[j].y);
                    gx[3] += wv[j] * hif(rr[j].y);
                    gx[4] += wv[j] * lof(rr[j].z);
                    gx[5] += wv[j] * hif(rr[j].z);
                    gx[6] += wv[j] * lof(rr[j].w);
                    gx[7] += wv[j] * hif(rr[j].w);
                }
        }
        float st = sa;                        // entries split across slots
        st += __shfl_xor(st, 16, 64);
        st += __shfl_xor(st, 32, 64);
        float inv = 1.0f / st;
        #pragma unroll
        for (int k = 0; k < 8; ++k) ax[k] += gx[k] * inv;
    }
    // reduce across slots; every lane ends with the full sum for its dims
    #pragma unroll
    for (int k = 0; k < 8; ++k) {
        ax[k] += __shfl_xor(ax[k], 16, 64);
        ax[k] += __shfl_xor(ax[k], 32, 64);
    }
    // per-wave LDS transpose (same-wave ds ordering, no barrier needed)
    if (slot == 0) {
        *(float4*)&xbuf[w][8 * sub]     = make_float4(ax[0], ax[1], ax[2], ax[3]);
        *(float4*)&xbuf[w][8 * sub + 4] = make_float4(ax[4], ax[5], ax[6], ax[7]);
    }
    float2 f2 = *(const float2*)&xbuf[w][2 * lane];
    float* dst = dsum + (size_t)d * H + 2 * lane;
    atomicAdd(dst,     f2.x);
    atomicAdd(dst + 1, f2.y);
}

// K4: one block (128 threads) per drug. fingerprint staged in LDS, each
// thread j dots its own w_out row (float4, L2-resident) + bias + ReLU.
// gcnt[d] == number of non-empty groups for drug d.
__global__ void k4_out(const float* __restrict__ dsum,
                       const int* __restrict__ gcnt,
                       const float* __restrict__ w_out,
                       const float* __restrict__ b_out,
                       float* __restrict__ out) {
    __shared__ float fp[H];
    int d = blockIdx.x;
    int j = threadIdx.x;
    int c = gcnt[d];
    float f = 0.f;
    if (c > 0) f = dsum[(size_t)d * H + j] / (float)c;
    fp[j] = f;
    __syncthreads();
    const float4* wrow = (const float4*)(w_out + (size_t)j * H);
    const float4* fvec = (const float4*)fp;
    float acc = 0.f;
    #pragma unroll
    for (int i = 0; i < H / 4; ++i) {
        float4 w4 = wrow[i];
        float4 f4 = fvec[i];
        acc += w4.x * f4.x + w4.y * f4.y + w4.z * f4.z + w4.w * f4.w;
    }
    acc += b_out[j];
    out[(size_t)d * H + j] = fmaxf(acc, 0.f);
}

extern "C" void kernel_launch(void* const* d_in, const int* in_sizes, int n_in,
                              void* d_out, int out_size, void* d_ws, size_t ws_size,
                              hipStream_t stream) {
    const float* protein_h = (const float*)d_in[0];
    const float* w_attn    = (const float*)d_in[1];
    const float* w_out     = (const float*)d_in[2];
    const float* b_out     = (const float*)d_in[3];
    const int*   prot_idx  = (const int*)d_in[4];
    const int*   group_ids = (const int*)d_in[5];
    const int*   g2d       = (const int*)d_in[6];

    const int E  = in_sizes[4];
    const int G  = in_sizes[6];
    const int NP = in_sizes[0] / H;

    // Workspace (~28.6 MB):
    // phb | psexp | pw(+16) | gs | ge | gl2 | [ZERO: gcnt dsum]
    __hip_bfloat16* phb = (__hip_bfloat16*)d_ws;          // NP*H bf16
    float*    psexp = (float*)(phb + (size_t)NP * H);     // NP
    unsigned* pw    = (unsigned*)(psexp + NP);            // E + 16
    int*      gs    = (int*)(pw + E + 16);                // G (zeroed in k1)
    int*      ge    = gs + G;                             // G
    int2*     gl2   = (int2*)(ge + G);                    // ND*MAXG
    int*      gcnt  = (int*)(gl2 + (size_t)ND * MAXG);    // ND   (zeroed in k1)
    float*    dsum  = (float*)(gcnt + ND);                // ND*H (zeroed in k1)

    // Per-protein exp(logit) + bf16 table + accumulator zeroing.
    int pw_blocks = (NP + 7) / 8;
    k_pscore_cvt<<<pw_blocks, 256, 0, stream>>>(protein_h, w_attn, psexp, phb,
                                                gcnt, gs, NP, G);

    // Streaming marks + fused per-entry stream (idx|bf16 weight).
    k_prep<<<(E + 255) / 256, 256, 0, stream>>>(group_ids, prot_idx, psexp,
                                                gs, ge, pw, E);

    // Per-group {start,len} -> drug lists.
    k_p2<<<(G + 255) / 256, 256, 0, stream>>>(gs, ge, g2d, gcnt, gl2, G);

    // Drug-major fused pooling: ND*CH waves, 4 waves per block.
    k_fused_drug<<<(ND * CH) / 4, 256, 0, stream>>>(phb, pw, gl2, gcnt, dsum);

    // Fingerprint + out_proj + ReLU.
    k4_out<<<ND, H, 0, stream>>>(dsum, gcnt, w_out, b_out, (float*)d_out);
}

// Round 17
// 143.480 us; speedup vs baseline: 8.6790x; 1.0298x over previous
//
#include <hip/hip_runtime.h>
#include <hip/hip_bf16.h>

#define H 128
#define ND 4096
#define CH 8      // waves (group-chunks) per drug
#define MAXG 128  // gl2 slots per drug (observed max ~77; 128 = 11 sigma)
#define ZDW (ND + ND * H)   // dwords to zero: gcnt | dsum

__device__ __forceinline__ float lof(unsigned u) { return __uint_as_float(u << 16); }
__device__ __forceinline__ float hif(unsigned u) { return __uint_as_float(u & 0xffff0000u); }

// Select component `slot` (0..3) of a uniform uint4 -- 3 v_cndmask.
__device__ __forceinline__ unsigned sel4(uint4 q, int slot) {
    unsigned a = (slot & 1) ? q.y : q.x;
    unsigned b = (slot & 1) ? q.w : q.z;
    return (slot & 2) ? b : a;
}

// K1: zero gcnt|dsum; psexp[p] = exp(ph[p].w_attn) + phb[p] = bf16(ph[p])
// (grid-stride rows, 2 per wave); boundary MARKS (grid-stride E, pure
// neighbor-compare streaming -- no serial walk). gs/ge are NOT pre-zeroed:
// k_p2 validates marks against gid directly (poison-proof, replay-proof).
__global__ void k1(const float* __restrict__ ph,
                   const float* __restrict__ w_attn,
                   const int* __restrict__ gid,
                   float* __restrict__ psexp,
                   __hip_bfloat16* __restrict__ phb,
                   int* __restrict__ zbase,
                   int* __restrict__ gs, int* __restrict__ ge,
                   int NP, int E) {
    int gt = blockIdx.x * blockDim.x + threadIdx.x;
    int nthr = gridDim.x * blockDim.x;
    for (int i = gt; i < ZDW; i += nthr) zbase[i] = 0;
    for (int t = gt; t < E; t += nthr) {
        int g = gid[t];
        int gp = (t > 0) ? gid[t - 1] : -1;
        int gn = (t + 1 < E) ? gid[t + 1] : -1;
        if (gp != g) gs[g] = t + 1;     // start+1
        if (gn != g) ge[g] = t + 1;     // end
    }
    int lane = threadIdx.x & 63;
    int half = lane >> 5;
    int l32  = lane & 31;
    int nw   = nthr >> 6;
    float4 wa = *(const float4*)(w_attn + 4 * l32);
    for (int r0 = (gt >> 6) * 2; r0 < NP; r0 += nw * 2) {
        int row = r0 + half;            // NP even -> row < NP
        float4 v = *(const float4*)(ph + (size_t)row * H + 4 * l32);
        __hip_bfloat16 b0 = __float2bfloat16(v.x);
        __hip_bfloat16 b1 = __float2bfloat16(v.y);
        __hip_bfloat16 b2 = __float2bfloat16(v.z);
        __hip_bfloat16 b3 = __float2bfloat16(v.w);
        ushort4 pk;
        pk.x = *(unsigned short*)&b0; pk.y = *(unsigned short*)&b1;
        pk.z = *(unsigned short*)&b2; pk.w = *(unsigned short*)&b3;
        *(ushort4*)(phb + (size_t)row * H + 4 * l32) = pk;
        float d = v.x * wa.x + v.y * wa.y + v.z * wa.z + v.w * wa.w;
        #pragma unroll
        for (int off = 16; off >= 1; off >>= 1) d += __shfl_xor(d, off, 64);
        if (l32 == 0) psexp[row] = __expf(d);  // raw exp: scores ~N(0,1), f32-safe
    }
}

// K_p2: t<E: pw[t] = prot_idx | bf16(exp-weight)<<16 (coalesced stream).
//       t<G: validate marks against gid (rejects poison; accepts stale-but-
//       identical replay values; empty groups can never validate) and append
//       {start,len} to the owning drug's list.
__global__ void k_p2(const int* __restrict__ gid,
                     const int* __restrict__ prot_idx,
                     const float* __restrict__ psexp,
                     const int* __restrict__ gs, const int* __restrict__ ge,
                     const int* __restrict__ g2d,
                     int* __restrict__ gcnt, int2* __restrict__ gl2,
                     unsigned* __restrict__ pw, int E, int G) {
    int t = blockIdx.x * blockDim.x + threadIdx.x;
    if (t < E) {
        int p = prot_idx[t];
        __hip_bfloat16 hb = __float2bfloat16(psexp[p]);
        pw[t] = (unsigned)p | ((unsigned)*(unsigned short*)&hb << 16);
    }
    if (t < G) {
        int s = gs[t], e = ge[t];
        bool ok = (s >= 1) && (s <= E) && (e >= s) && (e <= E);
        if (ok) ok = (gid[s - 1] == t) && (s == 1 || gid[s - 2] != t) &&
                     (gid[e - 1] == t) && (e == E || gid[e] != t);
        if (ok) {
            int d = g2d[t];
            int slot = atomicAdd(&gcnt[d], 1);
            if (slot < MAXG) gl2[d * MAXG + slot] = make_int2(s - 1, e - s + 1);
        }
    }
}

// K_fused_drug: one wave per (drug, chunk) -- r13/r16 hot loop with ONE
// addition: next-group gl2 prefetch (register software pipeline; the
// metadata latency hides under the current group's gathers/FMA). lane =
// (slot=lane>>4, sub=lane&15); scalar s_load pw quads; 3-cndmask lane
// distribution; uint4 gather = 4 complete 256B rows/instr; quad guards
// skip tail; shfl_xor denom; per-wave LDS transpose flush.
__global__ void k_fused_drug(const __hip_bfloat16* __restrict__ phb,
                             const unsigned* __restrict__ pw,
                             const int2* __restrict__ gl2,
                             const int* __restrict__ gcnt,
                             float* __restrict__ dsum) {
    __shared__ float xbuf[4][H];
    int w    = threadIdx.x >> 6;
    int lane = threadIdx.x & 63;
    int slot = lane >> 4;
    int sub  = lane & 15;
    int wid  = (blockIdx.x * blockDim.x + threadIdx.x) >> 6;
    wid = __builtin_amdgcn_readfirstlane(wid);   // wave-uniform -> SGPR
    int d = wid >> 3;          // wid / CH
    int c = wid & (CH - 1);
    if (d >= ND) return;
    int gn = gcnt[d];
    if (gn > MAXG) gn = MAXG;
    const int2* gl = gl2 + d * MAXG;
    const __hip_bfloat16* base = phb + sub * 8;
    float ax[8];
    #pragma unroll
    for (int k = 0; k < 8; ++k) ax[k] = 0.f;
    int2 A = (c < gn) ? gl[c] : make_int2(0, 0);
    for (int i = c; i < gn; i += CH) {
        int2 An = (i + CH < gn) ? gl[i + CH] : make_int2(0, 0);  // prefetch
        int s0  = __builtin_amdgcn_readfirstlane(A.x);
        int len = __builtin_amdgcn_readfirstlane(A.y);
        float sa = 0.f;
        float gx[8];
        #pragma unroll
        for (int k = 0; k < 8; ++k) gx[k] = 0.f;
        for (int e = 0; e < len; e += 16) {
            const uint4* pp = (const uint4*)(pw + s0 + e);  // uniform -> s_load
            uint4 q[4];
            q[0] = pp[0]; q[1] = pp[1]; q[2] = pp[2]; q[3] = pp[3];
            int rem = len - e;
            int p0 = (int)(q[0].x & 0xffffu);
            float wv[4]; int pv[4];
            #pragma unroll
            for (int j = 0; j < 4; ++j) {
                unsigned uv = sel4(q[j], slot);
                int ii = 4 * j + slot;
                bool valid = ii < rem;
                wv[j] = valid ? hif(uv) : 0.f;
                pv[j] = valid ? (int)(uv & 0xffffu) : p0;
            }
            uint4 rr[4];
            #pragma unroll
            for (int j = 0; j < 4; ++j)
                if (4 * j < rem) rr[j] = *(const uint4*)(base + (size_t)pv[j] * H);
            #pragma unroll
            for (int j = 0; j < 4; ++j)
                if (4 * j < rem) {
                    sa += wv[j];
                    gx[0] += wv[j] * lof(rr[j].x);
                    gx[1] += wv[j] * hif(rr[j].x);
                    gx[2] += wv[j] * lof(rr[j].y);
                    gx[3] += wv[j] * hif(rr[j].y);
                    gx[4] += wv[j] * lof(rr[j].z);
                    gx[5] += wv[j] * hif(rr[j].z);
                    gx[6] += wv[j] * lof(rr[j].w);
                    gx[7] += wv[j] * hif(rr[j].w);
                }
        }
        float st = sa;                        // entries split across slots
        st += __shfl_xor(st, 16, 64);
        st += __shfl_xor(st, 32, 64);
        float inv = 1.0f / st;
        #pragma unroll
        for (int k = 0; k < 8; ++k) ax[k] += gx[k] * inv;
        A = An;
    }
    // reduce across slots; every lane ends with the full sum for its dims
    #pragma unroll
    for (int k = 0; k < 8; ++k) {
        ax[k] += __shfl_xor(ax[k], 16, 64);
        ax[k] += __shfl_xor(ax[k], 32, 64);
    }
    // per-wave LDS transpose (same-wave ds ordering, no barrier needed)
    if (slot == 0) {
        *(float4*)&xbuf[w][8 * sub]     = make_float4(ax[0], ax[1], ax[2], ax[3]);
        *(float4*)&xbuf[w][8 * sub + 4] = make_float4(ax[4], ax[5], ax[6], ax[7]);
    }
    float2 f2 = *(const float2*)&xbuf[w][2 * lane];
    float* dst = dsum + (size_t)d * H + 2 * lane;
    atomicAdd(dst,     f2.x);
    atomicAdd(dst + 1, f2.y);
}

// K4: one block (128 threads) per drug. fingerprint staged in LDS, each
// thread j dots its own w_out row (float4, L2-resident) + bias + ReLU.
__global__ void k4_out(const float* __restrict__ dsum,
                       const int* __restrict__ gcnt,
                       const float* __restrict__ w_out,
                       const float* __restrict__ b_out,
                       float* __restrict__ out) {
    __shared__ float fp[H];
    int d = blockIdx.x;
    int j = threadIdx.x;
    int c = gcnt[d];
    float f = 0.f;
    if (c > 0) f = dsum[(size_t)d * H + j] / (float)c;
    fp[j] = f;
    __syncthreads();
    const float4* wrow = (const float4*)(w_out + (size_t)j * H);
    const float4* fvec = (const float4*)fp;
    float acc = 0.f;
    #pragma unroll
    for (int i = 0; i < H / 4; ++i) {
        float4 w4 = wrow[i];
        float4 f4 = fvec[i];
        acc += w4.x * f4.x + w4.y * f4.y + w4.z * f4.z + w4.w * f4.w;
    }
    acc += b_out[j];
    out[(size_t)d * H + j] = fmaxf(acc, 0.f);
}

extern "C" void kernel_launch(void* const* d_in, const int* in_sizes, int n_in,
                              void* d_out, int out_size, void* d_ws, size_t ws_size,
                              hipStream_t stream) {
    const float* protein_h = (const float*)d_in[0];
    const float* w_attn    = (const float*)d_in[1];
    const float* w_out     = (const float*)d_in[2];
    const float* b_out     = (const float*)d_in[3];
    const int*   prot_idx  = (const int*)d_in[4];
    const int*   group_ids = (const int*)d_in[5];
    const int*   g2d       = (const int*)d_in[6];

    const int E  = in_sizes[4];
    const int G  = in_sizes[6];
    const int NP = in_sizes[0] / H;

    // Workspace (~28.6 MB):
    // phb | psexp | pw(+16) | gs | ge | gl2 | [ZERO: gcnt dsum]
    __hip_bfloat16* phb = (__hip_bfloat16*)d_ws;          // NP*H bf16
    float*    psexp = (float*)(phb + (size_t)NP * H);     // NP
    unsigned* pw    = (unsigned*)(psexp + NP);            // E + 16
    int*      gs    = (int*)(pw + E + 16);                // G (validated, not zeroed)
    int*      ge    = gs + G;                             // G
    int2*     gl2   = (int2*)(ge + G);                    // ND*MAXG
    int*      gcnt  = (int*)(gl2 + (size_t)ND * MAXG);    // ND   (zeroed in k1)
    float*    dsum  = (float*)(gcnt + ND);                // ND*H (zeroed in k1)

    // Node 1: zero + per-protein exp(logit) + bf16 table + boundary marks.
    k1<<<4096, 256, 0, stream>>>(protein_h, w_attn, group_ids, psexp, phb,
                                 gcnt, gs, ge, NP, E);

    // Node 2: pw stream + validated group-list build.
    k_p2<<<(E + 255) / 256, 256, 0, stream>>>(group_ids, prot_idx, psexp,
                                              gs, ge, g2d, gcnt, gl2, pw, E, G);

    // Node 3: drug-major fused pooling.
    k_fused_drug<<<(ND * CH) / 4, 256, 0, stream>>>(phb, pw, gl2, gcnt, dsum);

    // Node 4: fingerprint + out_proj + ReLU.
    k4_out<<<ND, H, 0, stream>>>(dsum, gcnt, w_out, b_out, (float*)d_out);
}